// Round 1
// baseline (12059.907 us; speedup 1.0000x reference)
//
#include <hip/hip_runtime.h>
#include <math.h>

// Transformer-XL forward, round 0: correctness-first fp32 implementation.
// All GEMMs: 64x64 tile, 256 threads, 4x4 micro-tile, BK=16, LDS-staged.
// rel_shift handled analytically: BD[i,j] = BDmat[i, j-i+511] for j<=i+512.

namespace {

constexpr int BSZ = 4, QLEN = 512, MLEN = 512, KLEN = 1024;
constexpr int NHEAD = 16, DMODEL = 1024, DHEAD = 64, DINNER = 4096;
constexpr int NTOK = 32000, NLAYER = 6;
constexpr int ROWS = BSZ * QLEN;           // 2048
constexpr int VCH = 3200;                  // vocab chunk size (50*64)
constexpr int NCH = NTOK / VCH;            // 10

// ---------------- block reduce helpers (blockDim.x == 256) ----------------
__device__ __forceinline__ float blk_sum(float v, float* sred) {
#pragma unroll
  for (int o = 32; o > 0; o >>= 1) v += __shfl_down(v, o, 64);
  int w = threadIdx.x >> 6;
  __syncthreads();
  if ((threadIdx.x & 63) == 0) sred[w] = v;
  __syncthreads();
  return sred[0] + sred[1] + sred[2] + sred[3];
}
__device__ __forceinline__ float blk_max(float v, float* sred) {
#pragma unroll
  for (int o = 32; o > 0; o >>= 1) v = fmaxf(v, __shfl_down(v, o, 64));
  int w = threadIdx.x >> 6;
  __syncthreads();
  if ((threadIdx.x & 63) == 0) sred[w] = v;
  __syncthreads();
  return fmaxf(fmaxf(sred[0], sred[1]), fmaxf(sred[2], sred[3]));
}

// ---------------- misc small kernels ----------------
__global__ __launch_bounds__(256) void embed_k(const int* __restrict__ data,
    const float* __restrict__ emb, float* __restrict__ x) {
  int row = blockIdx.x;                       // 0..2047  (b*512+q)
  int tok = data[row];
  reinterpret_cast<float4*>(x + (size_t)row * DMODEL)[threadIdx.x] =
      reinterpret_cast<const float4*>(emb + (size_t)tok * DMODEL)[threadIdx.x];
}

__global__ __launch_bounds__(256) void pos_k(float* __restrict__ pos) {
  int p = blockIdx.x;                         // 0..1023
  float ps = (float)(KLEN - 1 - p);
  for (int m = threadIdx.x; m < DMODEL; m += 256) {
    int mi = (m < 512) ? m : m - 512;
    float invf = powf(10000.f, -(float)mi * (1.f / 512.f));
    float a = ps * invf;
    pos[(size_t)p * DMODEL + m] = (m < 512) ? sinf(a) : cosf(a);
  }
}

__global__ __launch_bounds__(256) void concat_k(const float* __restrict__ mem_l,
    const float* __restrict__ x, float* __restrict__ xm) {
  int g = blockIdx.x;                         // b*1024 + j, 0..4095
  int b = g >> 10, j = g & 1023;
  const float* src = (j < MLEN)
      ? mem_l + ((size_t)b * MLEN + j) * DMODEL
      : x + ((size_t)b * QLEN + (j - MLEN)) * DMODEL;
  reinterpret_cast<float4*>(xm + (size_t)g * DMODEL)[threadIdx.x] =
      reinterpret_cast<const float4*>(src)[threadIdx.x];
}

// ---------------- generic fp32 GEMM: C[M,N] = A[M,K] @ B[K,N] ----------------
// MODE: 0 plain, 1 +bias, 2 +bias+relu.  M,N % 64 == 0, K % 16 == 0.
template <int MODE>
__global__ __launch_bounds__(256) void gemm_rrr(const float* __restrict__ A,
    const float* __restrict__ B, const float* __restrict__ bias,
    float* __restrict__ C, int M, int N, int K) {
  __shared__ __align__(16) float As[16][68];
  __shared__ __align__(16) float Bs[16][68];
  int tid = threadIdx.x;
  int tx = tid & 15, ty = tid >> 4;
  int col0 = blockIdx.x * 64, row0 = blockIdx.y * 64;
  int ar = tid >> 2, ak = (tid & 3) * 4;      // A tile: 64 rows x 16 k
  int bk = tid >> 4, bc = (tid & 15) * 4;     // B tile: 16 k x 64 cols
  const float* Ap = A + (size_t)(row0 + ar) * K + ak;
  const float* Bp = B + (size_t)bk * N + col0 + bc;
  float acc[4][4] = {};
  for (int k0 = 0; k0 < K; k0 += 16) {
    float4 a = *reinterpret_cast<const float4*>(Ap + k0);
    As[ak + 0][ar] = a.x; As[ak + 1][ar] = a.y;
    As[ak + 2][ar] = a.z; As[ak + 3][ar] = a.w;
    *reinterpret_cast<float4*>(&Bs[bk][bc]) =
        *reinterpret_cast<const float4*>(Bp + (size_t)k0 * N);
    __syncthreads();
#pragma unroll
    for (int kk = 0; kk < 16; ++kk) {
      float4 av = *reinterpret_cast<const float4*>(&As[kk][ty * 4]);
      float4 bv = *reinterpret_cast<const float4*>(&Bs[kk][tx * 4]);
      acc[0][0] += av.x * bv.x; acc[0][1] += av.x * bv.y; acc[0][2] += av.x * bv.z; acc[0][3] += av.x * bv.w;
      acc[1][0] += av.y * bv.x; acc[1][1] += av.y * bv.y; acc[1][2] += av.y * bv.z; acc[1][3] += av.y * bv.w;
      acc[2][0] += av.z * bv.x; acc[2][1] += av.z * bv.y; acc[2][2] += av.z * bv.z; acc[2][3] += av.z * bv.w;
      acc[3][0] += av.w * bv.x; acc[3][1] += av.w * bv.y; acc[3][2] += av.w * bv.z; acc[3][3] += av.w * bv.w;
    }
    __syncthreads();
  }
  float4 bb = make_float4(0.f, 0.f, 0.f, 0.f);
  if (MODE >= 1) bb = *reinterpret_cast<const float4*>(bias + col0 + tx * 4);
#pragma unroll
  for (int m = 0; m < 4; ++m) {
    float4 o = make_float4(acc[m][0] + bb.x, acc[m][1] + bb.y,
                           acc[m][2] + bb.z, acc[m][3] + bb.w);
    if (MODE == 2) {
      o.x = fmaxf(o.x, 0.f); o.y = fmaxf(o.y, 0.f);
      o.z = fmaxf(o.z, 0.f); o.w = fmaxf(o.w, 0.f);
    }
    *reinterpret_cast<float4*>(C + (size_t)(row0 + ty * 4 + m) * N + col0 + tx * 4) = o;
  }
}

// ---------------- GEMM with B transposed: C[M,N] = A[M,K] @ Bt[N,K]^T ----------------
__global__ __launch_bounds__(256) void gemm_rtr(const float* __restrict__ A,
    const float* __restrict__ Bt, float* __restrict__ C, int M, int N, int K) {
  __shared__ __align__(16) float As[16][68];
  __shared__ __align__(16) float Bs[16][68];
  int tid = threadIdx.x;
  int tx = tid & 15, ty = tid >> 4;
  int col0 = blockIdx.x * 64, row0 = blockIdx.y * 64;
  int ar = tid >> 2, ak = (tid & 3) * 4;
  float acc[4][4] = {};
  for (int k0 = 0; k0 < K; k0 += 16) {
    float4 a = *reinterpret_cast<const float4*>(A + (size_t)(row0 + ar) * K + k0 + ak);
    As[ak + 0][ar] = a.x; As[ak + 1][ar] = a.y;
    As[ak + 2][ar] = a.z; As[ak + 3][ar] = a.w;
    float4 b = *reinterpret_cast<const float4*>(Bt + (size_t)(col0 + ar) * K + k0 + ak);
    Bs[ak + 0][ar] = b.x; Bs[ak + 1][ar] = b.y;
    Bs[ak + 2][ar] = b.z; Bs[ak + 3][ar] = b.w;
    __syncthreads();
#pragma unroll
    for (int kk = 0; kk < 16; ++kk) {
      float4 av = *reinterpret_cast<const float4*>(&As[kk][ty * 4]);
      float4 bv = *reinterpret_cast<const float4*>(&Bs[kk][tx * 4]);
      acc[0][0] += av.x * bv.x; acc[0][1] += av.x * bv.y; acc[0][2] += av.x * bv.z; acc[0][3] += av.x * bv.w;
      acc[1][0] += av.y * bv.x; acc[1][1] += av.y * bv.y; acc[1][2] += av.y * bv.z; acc[1][3] += av.y * bv.w;
      acc[2][0] += av.z * bv.x; acc[2][1] += av.z * bv.y; acc[2][2] += av.z * bv.z; acc[2][3] += av.z * bv.w;
      acc[3][0] += av.w * bv.x; acc[3][1] += av.w * bv.y; acc[3][2] += av.w * bv.z; acc[3][3] += av.w * bv.w;
    }
    __syncthreads();
  }
#pragma unroll
  for (int m = 0; m < 4; ++m) {
    float4 o = make_float4(acc[m][0], acc[m][1], acc[m][2], acc[m][3]);
    *reinterpret_cast<float4*>(C + (size_t)(row0 + ty * 4 + m) * N + col0 + tx * 4) = o;
  }
}

// ---------------- attention score GEMMs ----------------
// Per (b fixed by pointer, head n = blockIdx.z):
//   C_n[i][u] (+)= sum_d (A[i][n*64+d] + bias[n*64+d]) * Bm[u][n*64+d]
// SHIFT==0: write C[n][i][u] directly (AC term, u == j)
// SHIFT==1: scatter-add into C[n][i][u + i - 511] (BD term after rel_shift)
template <int SHIFT>
__global__ __launch_bounds__(256) void attn_ab(const float* __restrict__ A, int lda,
    const float* __restrict__ Bm, int ldb, const float* __restrict__ bias,
    float* __restrict__ C) {
  int n = blockIdx.z;
  int col0 = blockIdx.x * 64, row0 = blockIdx.y * 64;
  __shared__ __align__(16) float As[16][68];
  __shared__ __align__(16) float Bs[16][68];
  int tid = threadIdx.x;
  int tx = tid & 15, ty = tid >> 4;
  int r = tid >> 2, k4 = (tid & 3) * 4;
  float acc[4][4] = {};
  for (int k0 = 0; k0 < DHEAD; k0 += 16) {
    float4 a = *reinterpret_cast<const float4*>(
        A + (size_t)(row0 + r) * lda + n * DHEAD + k0 + k4);
    float4 bb = *reinterpret_cast<const float4*>(bias + n * DHEAD + k0 + k4);
    As[k4 + 0][r] = a.x + bb.x; As[k4 + 1][r] = a.y + bb.y;
    As[k4 + 2][r] = a.z + bb.z; As[k4 + 3][r] = a.w + bb.w;
    float4 b = *reinterpret_cast<const float4*>(
        Bm + (size_t)(col0 + r) * ldb + n * DHEAD + k0 + k4);
    Bs[k4 + 0][r] = b.x; Bs[k4 + 1][r] = b.y;
    Bs[k4 + 2][r] = b.z; Bs[k4 + 3][r] = b.w;
    __syncthreads();
#pragma unroll
    for (int kk = 0; kk < 16; ++kk) {
      float4 av = *reinterpret_cast<const float4*>(&As[kk][ty * 4]);
      float4 bv = *reinterpret_cast<const float4*>(&Bs[kk][tx * 4]);
      acc[0][0] += av.x * bv.x; acc[0][1] += av.x * bv.y; acc[0][2] += av.x * bv.z; acc[0][3] += av.x * bv.w;
      acc[1][0] += av.y * bv.x; acc[1][1] += av.y * bv.y; acc[1][2] += av.y * bv.z; acc[1][3] += av.y * bv.w;
      acc[2][0] += av.z * bv.x; acc[2][1] += av.z * bv.y; acc[2][2] += av.z * bv.z; acc[2][3] += av.z * bv.w;
      acc[3][0] += av.w * bv.x; acc[3][1] += av.w * bv.y; acc[3][2] += av.w * bv.z; acc[3][3] += av.w * bv.w;
    }
    __syncthreads();
  }
  float* Cb = C + (size_t)n * QLEN * KLEN;
  if (SHIFT == 0) {
#pragma unroll
    for (int m = 0; m < 4; ++m) {
      float4 o = make_float4(acc[m][0], acc[m][1], acc[m][2], acc[m][3]);
      *reinterpret_cast<float4*>(Cb + (size_t)(row0 + ty * 4 + m) * KLEN + col0 + tx * 4) = o;
    }
  } else {
#pragma unroll
    for (int m = 0; m < 4; ++m) {
      int i = row0 + ty * 4 + m;
#pragma unroll
      for (int jn = 0; jn < 4; ++jn) {
        int u = col0 + tx * 4 + jn;
        int j = u + i - (QLEN - 1);
        if (j >= 0 && j < KLEN) Cb[(size_t)i * KLEN + j] += acc[m][jn];
      }
    }
  }
}

// ---------------- softmax with causal prefix (valid j < i+513), scale 1/8 ----------------
__global__ __launch_bounds__(256) void softmax_k(float* __restrict__ P) {
  __shared__ float sred[4];
  int i = blockIdx.x, n = blockIdx.y, tid = threadIdx.x;
  float* row = P + ((size_t)n * QLEN + i) * KLEN;
  int L = i + MLEN + 1;
  float sv[4];
  float lm = -1e30f;
#pragma unroll
  for (int s = 0; s < 4; ++s) {
    int j = s * 256 + tid;
    float sc = (j < L) ? row[j] * 0.125f : -1e30f;
    sv[s] = sc;
    lm = fmaxf(lm, sc);
  }
  float m = blk_max(lm, sred);
  float ls = 0.f;
#pragma unroll
  for (int s = 0; s < 4; ++s) {
    int j = s * 256 + tid;
    float e = (j < L) ? expf(sv[s] - m) : 0.f;
    sv[s] = e; ls += e;
  }
  float inv = 1.f / blk_sum(ls, sred);
#pragma unroll
  for (int s = 0; s < 4; ++s) row[s * 256 + tid] = sv[s] * inv;
}

// ---------------- PV: out[i][n*64+d] = sum_j P[n][i][j] * V[j][n*64+d] ----------------
__global__ __launch_bounds__(256) void attn_pv(const float* __restrict__ P,
    const float* __restrict__ V, float* __restrict__ out) {
  int n = blockIdx.y, i0 = blockIdx.x * 8;
  __shared__ __align__(16) float pl[8][KLEN];
  __shared__ float red[4][8][64];
  int tid = threadIdx.x;
  for (int t = tid; t < 8 * KLEN; t += 256) {
    int il = t >> 10, j = t & (KLEN - 1);
    pl[il][j] = P[((size_t)n * QLEN + i0 + il) * KLEN + j];
  }
  __syncthreads();
  int d = tid & 63, part = tid >> 6;
  float acc[8] = {};
  const float* vp = V + n * DHEAD + d;
  for (int j = part * 256; j < part * 256 + 256; ++j) {
    float vv = vp[(size_t)j * (2 * DMODEL)];
#pragma unroll
    for (int il = 0; il < 8; ++il) acc[il] += pl[il][j] * vv;
  }
#pragma unroll
  for (int il = 0; il < 8; ++il) red[part][il][d] = acc[il];
  __syncthreads();
  if (part == 0) {
#pragma unroll
    for (int il = 0; il < 8; ++il) {
      float v = red[0][il][d] + red[1][il][d] + red[2][il][d] + red[3][il][d];
      out[(size_t)(i0 + il) * DMODEL + n * DHEAD + d] = v;
    }
  }
}

// ---------------- x = LayerNorm(x + t) * g + b ----------------
__global__ __launch_bounds__(256) void add_ln(float* __restrict__ x,
    const float* __restrict__ t, const float* __restrict__ g,
    const float* __restrict__ b) {
  __shared__ float sred[4];
  int row = blockIdx.x, tid = threadIdx.x;
  float4* xr = reinterpret_cast<float4*>(x + (size_t)row * DMODEL);
  const float4* tr = reinterpret_cast<const float4*>(t + (size_t)row * DMODEL);
  float4 v = xr[tid], u = tr[tid];
  v.x += u.x; v.y += u.y; v.z += u.z; v.w += u.w;
  float mu = blk_sum(v.x + v.y + v.z + v.w, sred) * (1.f / DMODEL);
  float dx = v.x - mu, dy = v.y - mu, dz = v.z - mu, dw = v.w - mu;
  float var = blk_sum(dx * dx + dy * dy + dz * dz + dw * dw, sred) * (1.f / DMODEL);
  float rs = rsqrtf(var + 1e-5f);
  float4 gv = reinterpret_cast<const float4*>(g)[tid];
  float4 bv = reinterpret_cast<const float4*>(b)[tid];
  float4 o = make_float4(dx * rs * gv.x + bv.x, dy * rs * gv.y + bv.y,
                         dz * rs * gv.z + bv.z, dw * rs * gv.w + bv.w);
  xr[tid] = o;
}

// ---------------- per-chunk logsumexp partials + target logit pick ----------------
__global__ __launch_bounds__(256) void chunk_lse(const float* __restrict__ cb,
    const int* __restrict__ target, int c, float2* __restrict__ partial,
    float* __restrict__ tl) {
  __shared__ float sred[4];
  int row = blockIdx.x, tid = threadIdx.x;
  const float* r = cb + (size_t)row * VCH;
  int tgt = target[row] - c * VCH;
  float lm = -1e30f;
  for (int j = tid; j < VCH; j += 256) {
    float v = r[j];
    lm = fmaxf(lm, v);
    if (j == tgt) tl[row] = v;
  }
  float m = blk_max(lm, sred);
  float ls = 0.f;
  for (int j = tid; j < VCH; j += 256) ls += expf(r[j] - m);
  float s = blk_sum(ls, sred);
  if (tid == 0) partial[row * NCH + c] = make_float2(m, s);
}

__global__ __launch_bounds__(256) void final_nll(const float2* __restrict__ partial,
    const float* __restrict__ tl, float* __restrict__ out) {
  int r = blockIdx.x * 256 + threadIdx.x;
  if (r >= ROWS) return;
  float m = -1e30f, s = 0.f;
#pragma unroll
  for (int c = 0; c < NCH; ++c) {
    float2 p = partial[r * NCH + c];
    float nm = fmaxf(m, p.x);
    s = s * expf(m - nm) + p.y * expf(p.x - nm);
    m = nm;
  }
  out[r] = m + logf(s) - tl[r];
}

}  // namespace

extern "C" void kernel_launch(void* const* d_in, const int* in_sizes, int n_in,
                              void* d_out, int out_size, void* d_ws, size_t ws_size,
                              hipStream_t stream) {
  const int* data    = (const int*)d_in[0];
  const int* target  = (const int*)d_in[1];
  const float* memory= (const float*)d_in[2];
  const float* emb   = (const float*)d_in[3];
  const float* Wq    = (const float*)d_in[4];
  const float* Wkv   = (const float*)d_in[5];
  const float* Wr    = (const float*)d_in[6];
  const float* Wo    = (const float*)d_in[7];
  const float* ffW1  = (const float*)d_in[8];
  const float* ffb1  = (const float*)d_in[9];
  const float* ffW2  = (const float*)d_in[10];
  const float* ffb2  = (const float*)d_in[11];
  const float* ln1g  = (const float*)d_in[12];
  const float* ln1b  = (const float*)d_in[13];
  const float* ln2g  = (const float*)d_in[14];
  const float* ln2b  = (const float*)d_in[15];
  const float* bw    = (const float*)d_in[16];
  const float* br    = (const float*)d_in[17];
  float* out = (float*)d_out;

  // workspace layout (floats); total ~31.5M floats ~126 MB
  float* ws  = (float*)d_ws;
  float* x   = ws;                        // [2048][1024]
  float* xm  = x   + (size_t)ROWS * DMODEL;          // [4096][1024]
  float* pos = xm  + (size_t)BSZ * KLEN * DMODEL;    // [1024][1024]
  float* q   = pos + (size_t)KLEN * DMODEL;          // [2048][1024]
  float* kvb = q   + (size_t)ROWS * DMODEL;          // [4096][2048]
  float* rkb = kvb + (size_t)BSZ * KLEN * 2 * DMODEL;// [1024][1024]
  float* vec = rkb + (size_t)KLEN * DMODEL;          // [2048][1024]
  float* tmp = vec + (size_t)ROWS * DMODEL;          // [2048][1024]
  float* sh  = tmp + (size_t)ROWS * DMODEL;          // [8.39M] AC / ff-mid / logits chunk
  float* part= sh  + (size_t)NHEAD * QLEN * KLEN;    // [2048][10] float2
  float* tl  = part + (size_t)ROWS * NCH * 2;        // [2048]

  embed_k<<<ROWS, 256, 0, stream>>>(data, emb, x);
  pos_k<<<KLEN, 256, 0, stream>>>(pos);

  for (int l = 0; l < NLAYER; ++l) {
    const float* Wq_l = Wq + (size_t)l * DMODEL * DMODEL;
    const float* Wkv_l= Wkv+ (size_t)l * DMODEL * 2 * DMODEL;
    const float* Wr_l = Wr + (size_t)l * DMODEL * DMODEL;
    const float* Wo_l = Wo + (size_t)l * DMODEL * DMODEL;
    const float* W1_l = ffW1 + (size_t)l * DMODEL * DINNER;
    const float* b1_l = ffb1 + (size_t)l * DINNER;
    const float* W2_l = ffW2 + (size_t)l * DINNER * DMODEL;
    const float* b2_l = ffb2 + (size_t)l * DMODEL;
    const float* mem_l= memory + (size_t)l * BSZ * MLEN * DMODEL;

    concat_k<<<BSZ * KLEN, 256, 0, stream>>>(mem_l, x, xm);
    gemm_rrr<0><<<dim3(16, 32), 256, 0, stream>>>(x,  Wq_l,  nullptr, q,   ROWS, DMODEL, DMODEL);
    gemm_rrr<0><<<dim3(32, 64), 256, 0, stream>>>(xm, Wkv_l, nullptr, kvb, BSZ * KLEN, 2 * DMODEL, DMODEL);
    gemm_rrr<0><<<dim3(16, 16), 256, 0, stream>>>(pos, Wr_l, nullptr, rkb, KLEN, DMODEL, DMODEL);

    for (int b = 0; b < BSZ; ++b) {
      const float* qb = q + (size_t)b * QLEN * DMODEL;
      const float* kb = kvb + (size_t)b * KLEN * 2 * DMODEL;
      // AC = (q+bw) @ k^T  -> sh[n][i][j]
      attn_ab<0><<<dim3(16, 8, NHEAD), 256, 0, stream>>>(qb, DMODEL, kb, 2 * DMODEL, bw, sh);
      // BD = (q+br) @ rk^T, scatter-added at shifted j = u + i - 511
      attn_ab<1><<<dim3(16, 8, NHEAD), 256, 0, stream>>>(qb, DMODEL, rkb, DMODEL, br, sh);
      softmax_k<<<dim3(QLEN, NHEAD), 256, 0, stream>>>(sh);
      attn_pv<<<dim3(QLEN / 8, NHEAD), 256, 0, stream>>>(sh, kb + DMODEL,
          vec + (size_t)b * QLEN * DMODEL);
    }

    gemm_rrr<0><<<dim3(16, 32), 256, 0, stream>>>(vec, Wo_l, nullptr, tmp, ROWS, DMODEL, DMODEL);
    add_ln<<<ROWS, 256, 0, stream>>>(x, tmp, ln1g + (size_t)l * DMODEL, ln1b + (size_t)l * DMODEL);
    gemm_rrr<2><<<dim3(64, 32), 256, 0, stream>>>(x, W1_l, b1_l, sh, ROWS, DINNER, DMODEL);
    gemm_rrr<1><<<dim3(16, 32), 256, 0, stream>>>(sh, W2_l, b2_l, tmp, ROWS, DMODEL, DINNER);
    add_ln<<<ROWS, 256, 0, stream>>>(x, tmp, ln2g + (size_t)l * DMODEL, ln2b + (size_t)l * DMODEL);
  }

  // tied-embedding logits in 10 chunks of 3200 + streamed logsumexp
  for (int c = 0; c < NCH; ++c) {
    gemm_rtr<<<dim3(VCH / 64, ROWS / 64), 256, 0, stream>>>(x, emb + (size_t)c * VCH * DMODEL,
        sh, ROWS, VCH, DMODEL);
    chunk_lse<<<ROWS, 256, 0, stream>>>(sh, target, c, (float2*)part, tl);
  }
  final_nll<<<(ROWS + 255) / 256, 256, 0, stream>>>((const float2*)part, tl, out);
}